// Round 1
// baseline (294.330 us; speedup 1.0000x reference)
//
#include <hip/hip_runtime.h>
#include <math.h>

#define NB 8
#define NS 1024
#define NT 1024
#define NE 256
#define NHEADS 8
#define DH 32

// ws layout in float units
#define WS_TRGPROJ 0
#define WS_SSRC    (NB * NT * NHEADS * DH)            // 2097152
#define WS_STRG    (WS_SSRC + NB * NS * NHEADS)       // +65536
#define WS_FLAG    (WS_STRG + NB * NT * NHEADS)       // int flag lives here

// ---------------------------------------------------------------------------
// Probe: decide whether bool masks are stored as int32 (flag=1) or uint8
// (flag=0). View trg_mask as dwords: int32-bool => first 2048 dwords all in
// {0,1}; uint8-bool => packed random bytes => some dword > 1 w.p. ~1.
// Reads only 8 KB, in-bounds for either layout.
// ---------------------------------------------------------------------------
__global__ void probe_mask_kernel(const unsigned* __restrict__ mask_dw,
                                  int* __restrict__ flag) {
    __shared__ int s_ok;
    if (threadIdx.x == 0) s_ok = 1;
    __syncthreads();
    for (int i = threadIdx.x; i < 2048; i += blockDim.x) {
        if (mask_dw[i] > 1u) s_ok = 0;   // benign race, all writers write 0
    }
    __syncthreads();
    if (threadIdx.x == 0) *flag = s_ok;
}

// ---------------------------------------------------------------------------
// proj_score: Y[row, :] = X[row, :] @ W  (E x E), optional store of Y,
// optional per-head score[row,h] = sum_d Y[row, h*32+d] * a[h*32+d].
// Block: 256 threads, 16 rows. Thread owns one output column.
// Safe for in-place X==proj (rows staged to LDS before any write).
// ---------------------------------------------------------------------------
__global__ __launch_bounds__(256) void proj_score_kernel(
    const float* __restrict__ X, const float* __restrict__ W,
    const float* __restrict__ a, float* __restrict__ proj,
    float* __restrict__ score) {
    __shared__ float xt[16][NE];
    const int tid = threadIdx.x;
    const int row0 = blockIdx.x * 16;

    for (int r = 0; r < 16; ++r)
        xt[r][tid] = X[(size_t)(row0 + r) * NE + tid];
    __syncthreads();

    float acc[16];
#pragma unroll
    for (int r = 0; r < 16; ++r) acc[r] = 0.f;

    for (int e0 = 0; e0 < NE; e0 += 4) {
        const float w0 = W[(size_t)(e0 + 0) * NE + tid];
        const float w1 = W[(size_t)(e0 + 1) * NE + tid];
        const float w2 = W[(size_t)(e0 + 2) * NE + tid];
        const float w3 = W[(size_t)(e0 + 3) * NE + tid];
#pragma unroll
        for (int r = 0; r < 16; ++r) {
            const float4 x = *(const float4*)&xt[r][e0];
            acc[r] += x.x * w0 + x.y * w1 + x.z * w2 + x.w * w3;
        }
    }

    if (proj) {
        for (int r = 0; r < 16; ++r)
            proj[(size_t)(row0 + r) * NE + tid] = acc[r];
    }

    if (score) {
        const float av = a[tid];           // a is (NH, DH) flat = 256 floats
        const int h = tid >> 5;
#pragma unroll
        for (int r = 0; r < 16; ++r) {
            float v = acc[r] * av;
            v += __shfl_xor(v, 1);
            v += __shfl_xor(v, 2);
            v += __shfl_xor(v, 4);
            v += __shfl_xor(v, 8);
            v += __shfl_xor(v, 16);
            if ((tid & 31) == 0)
                score[(size_t)(row0 + r) * NHEADS + h] = v;
        }
    }
}

// ---------------------------------------------------------------------------
// softmax + attn write. Grid: 8*8*16 blocks = (b, h, s-tile of 64).
// 4 waves x 16 rows each; lane j owns t = j + 64k, k=0..15.
// scores[s,t] = leaky(score_src[s] + score_trg[t]); mask; softmax over t.
// ---------------------------------------------------------------------------
__global__ __launch_bounds__(256) void softmax_attn_kernel(
    const float* __restrict__ ssrc, const float* __restrict__ strg,
    const void* __restrict__ smask, const void* __restrict__ tmask,
    const int* __restrict__ flag_p, float* __restrict__ attn) {
    const int blk = blockIdx.x;
    const int stile = blk & 15;
    const int h = (blk >> 4) & 7;
    const int b = blk >> 7;
    const int tid = threadIdx.x;
    const int lane = tid & 63;
    const int wave = tid >> 6;
    const int flag = *flag_p;

    __shared__ float s_strg[NT];
    __shared__ float s_tm[NT];
    for (int t = tid; t < NT; t += 256) {
        s_strg[t] = strg[((size_t)b * NT + t) * NHEADS + h];
        const bool mv = flag ? (((const int*)tmask)[b * NT + t] != 0)
                             : (((const unsigned char*)tmask)[b * NT + t] != 0);
        s_tm[t] = mv ? 1.f : 0.f;
    }
    __syncthreads();

    const int s0 = stile * 64;
    for (int i = 0; i < 16; ++i) {
        const int r = wave * 16 + i;
        const int srow = s0 + r;
        const float ss = ssrc[((size_t)b * NS + srow) * NHEADS + h];
        const bool rowv = flag ? (((const int*)smask)[b * NS + srow] != 0)
                               : (((const unsigned char*)smask)[b * NS + srow] != 0);
        float sc[16];
        float m = -INFINITY;
#pragma unroll
        for (int k = 0; k < 16; ++k) {
            const int t = lane + 64 * k;
            float v = ss + s_strg[t];
            v = (v >= 0.f) ? v : 0.2f * v;     // LeakyReLU
            sc[k] = v;
            if (s_tm[t] != 0.f) m = fmaxf(m, v);
        }
#pragma unroll
        for (int off = 32; off >= 1; off >>= 1)
            m = fmaxf(m, __shfl_xor(m, off));

        float p[16];
        float sum = 0.f;
#pragma unroll
        for (int k = 0; k < 16; ++k) {
            const int t = lane + 64 * k;
            float pv = __expf(sc[k] - m);
            pv = (s_tm[t] != 0.f) ? pv : 0.f;
            p[k] = pv;
            sum += pv;
        }
#pragma unroll
        for (int off = 32; off >= 1; off >>= 1)
            sum += __shfl_xor(sum, off);

        const float inv = (rowv && sum > 0.f) ? 1.f / sum : 0.f;
        float* arow = attn + ((size_t)(b * NHEADS + h) * NS + srow) * NT;
#pragma unroll
        for (int k = 0; k < 16; ++k)
            arow[lane + 64 * k] = p[k] * inv;
    }
}

// ---------------------------------------------------------------------------
// aggregation: C[64s x 32d] = attn_tile[64s x 1024t] @ trg_proj[b,:,h,:]
// Grid: 8*8*16 blocks = (b, h, s-tile). LDS-tiled over t in chunks of 64.
// Writes aggregated into out[0:2M] region (later overwritten in-place by K4).
// ---------------------------------------------------------------------------
__global__ __launch_bounds__(256) void agg_kernel(
    const float* __restrict__ attn, const float* __restrict__ tproj,
    float* __restrict__ agg) {
    const int blk = blockIdx.x;
    const int stile = blk & 15;
    const int h = (blk >> 4) & 7;
    const int b = blk >> 7;
    const int tid = threadIdx.x;

    __shared__ float at[64][64];
    __shared__ float bt[64][DH];

    const int d = tid & 31;
    const int sg = tid >> 5;                 // 0..7
    float acc[8];
#pragma unroll
    for (int r = 0; r < 8; ++r) acc[r] = 0.f;

    const int s0 = stile * 64;
    const float* abase = attn + ((size_t)(b * NHEADS + h) * NS + s0) * NT;

    for (int tc = 0; tc < 16; ++tc) {
        const int t0 = tc * 64;
#pragma unroll
        for (int i = 0; i < 16; ++i) {
            const int idx = tid + 256 * i;
            const int sl = idx >> 6, tl = idx & 63;
            at[sl][tl] = abase[(size_t)sl * NT + t0 + tl];
        }
#pragma unroll
        for (int i = 0; i < 8; ++i) {
            const int idx = tid + 256 * i;
            const int tl = idx >> 5, dl = idx & 31;
            bt[tl][dl] = tproj[(((size_t)b * NT + t0 + tl) * NHEADS + h) * DH + dl];
        }
        __syncthreads();
        for (int tl = 0; tl < 64; ++tl) {
            const float bv = bt[tl][d];
#pragma unroll
            for (int r = 0; r < 8; ++r)
                acc[r] += at[sg + 8 * r][tl] * bv;
        }
        __syncthreads();
    }

#pragma unroll
    for (int r = 0; r < 8; ++r) {
        const int srow = s0 + sg + 8 * r;
        agg[((size_t)b * NS + srow) * NE + h * DH + d] = acc[r];
    }
}

extern "C" void kernel_launch(void* const* d_in, const int* in_sizes, int n_in,
                              void* d_out, int out_size, void* d_ws, size_t ws_size,
                              hipStream_t stream) {
    const float* src   = (const float*)d_in[0];
    const float* trg   = (const float*)d_in[1];
    const void*  smask = d_in[2];
    const void*  tmask = d_in[3];
    const float* Wsrc  = (const float*)d_in[4];
    const float* Wtrg  = (const float*)d_in[5];
    const float* asrc  = (const float*)d_in[6];
    const float* atrg  = (const float*)d_in[7];
    const float* Wout  = (const float*)d_in[8];

    float* out  = (float*)d_out;
    float* attn = out + (size_t)NB * NS * NE;   // second output, (B,NH,Ns,Nt)

    float* ws     = (float*)d_ws;
    float* tproj  = ws + WS_TRGPROJ;
    float* ssrc_s = ws + WS_SSRC;
    float* strg_s = ws + WS_STRG;
    int*   flag   = (int*)(ws + WS_FLAG);

    // 0) probe bool-mask storage layout
    probe_mask_kernel<<<1, 256, 0, stream>>>((const unsigned*)tmask, flag);

    // 1) trg projection (stored) + score_trg
    proj_score_kernel<<<(NB * NT) / 16, 256, 0, stream>>>(
        trg, Wtrg, atrg, tproj, strg_s);

    // 2) src: score_src only (projection not needed downstream)
    proj_score_kernel<<<(NB * NS) / 16, 256, 0, stream>>>(
        src, Wsrc, asrc, nullptr, ssrc_s);

    // 3) softmax + write attn output
    softmax_attn_kernel<<<NB * NHEADS * (NS / 64), 256, 0, stream>>>(
        ssrc_s, strg_s, smask, tmask, flag, attn);

    // 4) aggregation into out[0:2M] (scratch for the final GEMM)
    agg_kernel<<<NB * NHEADS * (NS / 64), 256, 0, stream>>>(attn, tproj, out);

    // 5) output = aggregated @ W_out, in-place over out[0:2M]
    proj_score_kernel<<<(NB * NS) / 16, 256, 0, stream>>>(
        out, Wout, asrc, out, nullptr);
}

// Round 2
// 170.469 us; speedup vs baseline: 1.7266x; 1.7266x over previous
//
#include <hip/hip_runtime.h>
#include <math.h>

#define NB 8
#define NS 1024
#define NT 1024
#define NE 256
#define NHEADS 8
#define DH 32

typedef __attribute__((ext_vector_type(8))) short short8;
typedef __attribute__((ext_vector_type(4))) float f32x4;

// ws layout (float units)
// [0 .. 1048576)   : tproj_bf16 (2M ushorts = 4 MB)
// [1048576 ..)     : ssrc scores (65536 f)
// then strg scores (65536 f), then flag (int)
#define WS_SSRC 1048576
#define WS_STRG (WS_SSRC + NB * NS * NHEADS)
#define WS_FLAG (WS_STRG + NB * NT * NHEADS)

__device__ __forceinline__ unsigned short f2bf(float f) {
    union { float f; unsigned u; } x; x.f = f;
    unsigned u = x.u;
    return (unsigned short)((u + 0x7FFFu + ((u >> 16) & 1u)) >> 16);
}

// ---------------------------------------------------------------------------
// Probe bool-mask storage: int32 (flag=1) vs uint8 (flag=0).
// ---------------------------------------------------------------------------
__global__ void probe_mask_kernel(const unsigned* __restrict__ mask_dw,
                                  int* __restrict__ flag) {
    __shared__ int s_ok;
    if (threadIdx.x == 0) s_ok = 1;
    __syncthreads();
    for (int i = threadIdx.x; i < 2048; i += blockDim.x) {
        if (mask_dw[i] > 1u) s_ok = 0;
    }
    __syncthreads();
    if (threadIdx.x == 0) *flag = s_ok;
}

// ---------------------------------------------------------------------------
// proj_score: Y[row,:] = X[row,:] @ W (256x256); optional f32 store, optional
// bf16 store, optional per-head score. 16 rows/block, thread owns one column.
// In-place safe for X==proj (rows staged in LDS first).
// ---------------------------------------------------------------------------
__global__ __launch_bounds__(256) void proj_score_kernel(
    const float* __restrict__ X, const float* __restrict__ W,
    const float* __restrict__ a, float* __restrict__ proj,
    unsigned short* __restrict__ proj_bf, float* __restrict__ score) {
    __shared__ float xt[16][NE];
    const int tid = threadIdx.x;
    const int row0 = blockIdx.x * 16;

    for (int r = 0; r < 16; ++r)
        xt[r][tid] = X[(size_t)(row0 + r) * NE + tid];
    __syncthreads();

    float acc[16];
#pragma unroll
    for (int r = 0; r < 16; ++r) acc[r] = 0.f;

    for (int e0 = 0; e0 < NE; e0 += 4) {
        const float w0 = W[(size_t)(e0 + 0) * NE + tid];
        const float w1 = W[(size_t)(e0 + 1) * NE + tid];
        const float w2 = W[(size_t)(e0 + 2) * NE + tid];
        const float w3 = W[(size_t)(e0 + 3) * NE + tid];
#pragma unroll
        for (int r = 0; r < 16; ++r) {
            const float4 x = *(const float4*)&xt[r][e0];
            acc[r] += x.x * w0 + x.y * w1 + x.z * w2 + x.w * w3;
        }
    }

    if (proj) {
#pragma unroll
        for (int r = 0; r < 16; ++r)
            proj[(size_t)(row0 + r) * NE + tid] = acc[r];
    }
    if (proj_bf) {
#pragma unroll
        for (int r = 0; r < 16; ++r)
            proj_bf[(size_t)(row0 + r) * NE + tid] = f2bf(acc[r]);
    }
    if (score) {
        const float av = a[tid];
        const int h = tid >> 5;
#pragma unroll
        for (int r = 0; r < 16; ++r) {
            float v = acc[r] * av;
            v += __shfl_xor(v, 1);
            v += __shfl_xor(v, 2);
            v += __shfl_xor(v, 4);
            v += __shfl_xor(v, 8);
            v += __shfl_xor(v, 16);
            if ((tid & 31) == 0)
                score[(size_t)(row0 + r) * NHEADS + h] = v;
        }
    }
}

// ---------------------------------------------------------------------------
// Fused softmax + attn write + aggregation (bf16 MFMA).
// Block = (b, h, stile of 64 s-rows), 4 waves x 16 rows.
// Lane layout == MFMA A-frag layout: row = lane&15, k = (lane>>4)*8 + e.
// No row-max (scores O(10), exp safe); masked t folded to -1e30 in LDS;
// fully-masked / invalid rows via inv = 0.
// agg (normalized) goes to out[0:2M] for the final in-place proj.
// ---------------------------------------------------------------------------
__global__ __launch_bounds__(256) void fused_softmax_agg_kernel(
    const float* __restrict__ ssrc, const float* __restrict__ strg,
    const void* __restrict__ smask, const void* __restrict__ tmask,
    const int* __restrict__ flag_p, const unsigned short* __restrict__ Vb,
    float* __restrict__ attn, float* __restrict__ agg) {
    const int blk = blockIdx.x;
    const int stile = blk & 15;
    const int h = (blk >> 4) & 7;
    const int b = blk >> 7;
    const int tid = threadIdx.x;
    const int lane = tid & 63;
    const int wave = tid >> 6;
    const int flag = *flag_p;

    __shared__ float s_sm[NT];   // strg score with mask folded in
    for (int t = tid; t < NT; t += 256) {
        const bool mv = flag ? (((const int*)tmask)[b * NT + t] != 0)
                             : (((const unsigned char*)tmask)[b * NT + t] != 0);
        s_sm[t] = mv ? strg[((size_t)b * NT + t) * NHEADS + h] : -1e30f;
    }
    __syncthreads();

    const int r = lane & 15;          // A row / B col / agg d-offset
    const int g = lane >> 4;          // k-group
    const int srow = stile * 64 + wave * 16 + r;
    const float ss = ssrc[((size_t)b * NS + srow) * NHEADS + h];
    const bool rowv = flag ? (((const int*)smask)[b * NS + srow] != 0)
                           : (((const unsigned char*)smask)[b * NS + srow] != 0);

    // pass 1: row sum of exp(leaky(score))
    float sum = 0.f;
    for (int c = 0; c < 32; ++c) {
        const int tb = c * 32 + g * 8;
        const float4 v0 = *(const float4*)&s_sm[tb];
        const float4 v1 = *(const float4*)&s_sm[tb + 4];
        const float vv[8] = {v0.x, v0.y, v0.z, v0.w, v1.x, v1.y, v1.z, v1.w};
#pragma unroll
        for (int e = 0; e < 8; ++e) {
            float v = ss + vv[e];
            v = (v >= 0.f) ? v : 0.2f * v;
            sum += __expf(v);
        }
    }
    sum += __shfl_xor(sum, 16);
    sum += __shfl_xor(sum, 32);
    const float inv = (rowv && sum > 0.f) ? 1.f / sum : 0.f;

    // pass 2: normalized p -> attn store + MFMA accumulate against V (bf16)
    f32x4 acc0 = {0.f, 0.f, 0.f, 0.f};
    f32x4 acc1 = {0.f, 0.f, 0.f, 0.f};
    float* arow = attn + ((size_t)((b * NHEADS + h) * NS) + srow) * NT;
    const unsigned short* vb = Vb + (size_t)b * NT * NE + h * DH;  // [t*256 + d]

    for (int c = 0; c < 32; ++c) {
        const int tb = c * 32 + g * 8;
        const float4 v0 = *(const float4*)&s_sm[tb];
        const float4 v1 = *(const float4*)&s_sm[tb + 4];
        const float vv[8] = {v0.x, v0.y, v0.z, v0.w, v1.x, v1.y, v1.z, v1.w};
        float p[8];
#pragma unroll
        for (int e = 0; e < 8; ++e) {
            float v = ss + vv[e];
            v = (v >= 0.f) ? v : 0.2f * v;
            p[e] = __expf(v) * inv;
        }
        const float4 o0 = {p[0], p[1], p[2], p[3]};
        const float4 o1 = {p[4], p[5], p[6], p[7]};
        *(float4*)(arow + tb) = o0;
        *(float4*)(arow + tb + 4) = o1;

        short8 af, bf0, bf1;
#pragma unroll
        for (int e = 0; e < 8; ++e) {
            af[e] = (short)f2bf(p[e]);
            const size_t o = (size_t)(tb + e) * NE + r;
            bf0[e] = (short)vb[o];
            bf1[e] = (short)vb[o + 16];
        }
        acc0 = __builtin_amdgcn_mfma_f32_16x16x32_bf16(af, bf0, acc0, 0, 0, 0);
        acc1 = __builtin_amdgcn_mfma_f32_16x16x32_bf16(af, bf1, acc1, 0, 0, 0);
    }

    // epilogue: C layout col=lane&15, row=(lane>>4)*4+reg
    const int orow = stile * 64 + wave * 16 + g * 4;
    float* ab = agg + ((size_t)b * NS + orow) * NE + h * DH + r;
#pragma unroll
    for (int j = 0; j < 4; ++j) {
        ab[(size_t)j * NE] = acc0[j];
        ab[(size_t)j * NE + 16] = acc1[j];
    }
}

extern "C" void kernel_launch(void* const* d_in, const int* in_sizes, int n_in,
                              void* d_out, int out_size, void* d_ws, size_t ws_size,
                              hipStream_t stream) {
    const float* src   = (const float*)d_in[0];
    const float* trg   = (const float*)d_in[1];
    const void*  smask = d_in[2];
    const void*  tmask = d_in[3];
    const float* Wsrc  = (const float*)d_in[4];
    const float* Wtrg  = (const float*)d_in[5];
    const float* asrc  = (const float*)d_in[6];
    const float* atrg  = (const float*)d_in[7];
    const float* Wout  = (const float*)d_in[8];

    float* out  = (float*)d_out;
    float* attn = out + (size_t)NB * NS * NE;

    float* ws = (float*)d_ws;
    unsigned short* tproj_bf = (unsigned short*)d_ws;
    float* ssrc_s = ws + WS_SSRC;
    float* strg_s = ws + WS_STRG;
    int*   flag   = (int*)(ws + WS_FLAG);

    // 0) probe mask layout
    probe_mask_kernel<<<1, 256, 0, stream>>>((const unsigned*)tmask, flag);

    // 1) trg projection -> bf16 V + score_trg
    proj_score_kernel<<<(NB * NT) / 16, 256, 0, stream>>>(
        trg, Wtrg, atrg, nullptr, tproj_bf, strg_s);

    // 2) src: score_src only
    proj_score_kernel<<<(NB * NS) / 16, 256, 0, stream>>>(
        src, Wsrc, asrc, nullptr, nullptr, ssrc_s);

    // 3) fused softmax + attn write + aggregation (into out[0:2M])
    fused_softmax_agg_kernel<<<NB * NHEADS * (NS / 64), 256, 0, stream>>>(
        ssrc_s, strg_s, smask, tmask, flag, tproj_bf, attn, out);

    // 4) output = aggregated @ W_out, in-place
    proj_score_kernel<<<(NB * NS) / 16, 256, 0, stream>>>(
        out, Wout, nullptr, out, nullptr, nullptr);
}